// Round 2
// baseline (24777.278 us; speedup 1.0000x reference)
//
#include <hip/hip_runtime.h>

#define NN 64
#define LD 65
#define NPAIR 32
#define BLOCK 256
#define MAXSWEEP 11
#define EPSF 1e-6f
#define TRI 2080
#define BATCH 4096
#define MU_OFF 16777216
#define LV_OFF 16908288
#define RELTOL_FULL 4e-11f
#define RELTOL_VALS 1e-8f
#define GRID_MAIN 1024

__device__ __forceinline__ int triOff(int i) { return (i * (129 - i)) >> 1; }

__device__ __forceinline__ float bn_leaky(float h, float g, float bb) {
  h = (h >= 0.0f) ? h : 0.2f * h;
  return h * (1.0f / sqrtf(1.0f + 1e-5f)) * g + bb;
}

// Parallel cyclic Jacobi, 64x64 symmetric in LDS (ld=65), with wave-uniform
// rotation skipping. Pair k of round r: k==0 -> (63, r); else ((r+k)%63, (r+63-k)%63).
// Each wave owns pairs {wv, wv+4, ..., wv+28} -> skip branches are wave-uniform.
// Terminates when an entire sweep performs zero rotations, which implies
// off^2 = 2*sum(apq^2) <= 2*2016*thr ~= fro2*relTol.
template<bool WITH_V>
__device__ void jacobi64(float* A, float* V, float2* csb, unsigned* flgs,
                         float* red, float relTol)
{
  const int tid = threadIdx.x;
  const int wv  = tid >> 6;   // wave id 0..3
  const int j   = tid & 63;

  if (WITH_V) {
    for (int idx = tid; idx < NN * LD; idx += BLOCK) V[idx] = 0.0f;
  }

  // Frobenius^2 (rotation invariant) -> skip threshold
  float fp = 0.0f;
  for (int idx = tid; idx < NN * NN; idx += BLOCK) {
    float a = A[(idx >> 6) * LD + (idx & 63)];
    fp += a * a;
  }
  red[tid] = fp;
  __syncthreads();
  for (int s2 = BLOCK / 2; s2 > 0; s2 >>= 1) {
    if (tid < s2) red[tid] += red[tid + s2];
    __syncthreads();
  }
  const float thr = red[0] * (relTol * (1.0f / 4096.0f)) + 1e-35f;
  if (WITH_V && tid < NN) V[tid * LD + tid] = 1.0f;
  __syncthreads();

  for (int sweep = 0; sweep < MAXSWEEP; ++sweep) {
    bool anyrot = false;
    for (int r = 0; r < 63; ++r) {
      const int buf = r & 1;
      bool rot = false;
      if (tid < NPAIR) {
        int p, q;
        if (tid == 0) { p = 63; q = r; }
        else {
          p = r + tid;      if (p >= 63) p -= 63;
          q = r + 63 - tid; if (q >= 63) q -= 63;
        }
        if (p > q) { int t = p; p = q; q = t; }
        float app = A[p * LD + p], aqq = A[q * LD + q], apq = A[p * LD + q];
        float c = 1.0f, s = 0.0f;
        rot = (apq * apq > thr);
        if (rot) {
          float th = (aqq - app) / (2.0f * apq);
          float t = 1.0f / (fabsf(th) + sqrtf(th * th + 1.0f));
          if (th < 0.0f) t = -t;
          c = 1.0f / sqrtf(t * t + 1.0f);
          s = t * c;
        }
        csb[buf * NPAIR + tid] = make_float2(c, s);
      }
      if (tid < 64) {  // wave 0 ballots; lanes 32..63 contribute 0
        unsigned long long bal = __ballot(rot);
        if (tid == 0) flgs[buf] = (unsigned)bal;
      }
      __syncthreads();               // B1

      const unsigned m = flgs[buf];
      if (m != 0u) {
        anyrot = true;
        const unsigned fullmask = 0x11111111u << wv;
        const bool full = (m & fullmask) == fullmask;

        float cc[8], ss[8]; int pp[8], qq[8];
        #pragma unroll
        for (int it = 0; it < 8; ++it) {
          const int k = wv + (it << 2);
          float2 cs = csb[buf * NPAIR + k];
          cc[it] = cs.x; ss[it] = cs.y;
          int p, q;
          if (k == 0) { p = 63; q = r; }
          else {
            p = r + k;      if (p >= 63) p -= 63;
            q = r + 63 - k; if (q >= 63) q -= 63;
          }
          if (p > q) { int t2 = p; p = q; q = t2; }
          pp[it] = p; qq[it] = q;
        }

        // row phase
        if (full) {
          float ap[8], aq[8];
          #pragma unroll
          for (int it = 0; it < 8; ++it) {
            ap[it] = A[pp[it] * LD + j];
            aq[it] = A[qq[it] * LD + j];
          }
          #pragma unroll
          for (int it = 0; it < 8; ++it) {
            A[pp[it] * LD + j] = cc[it] * ap[it] - ss[it] * aq[it];
            A[qq[it] * LD + j] = ss[it] * ap[it] + cc[it] * aq[it];
          }
        } else {
          #pragma unroll
          for (int it = 0; it < 8; ++it) {
            if ((m >> (wv + (it << 2))) & 1u) {
              float ap = A[pp[it] * LD + j], aq = A[qq[it] * LD + j];
              A[pp[it] * LD + j] = cc[it] * ap - ss[it] * aq;
              A[qq[it] * LD + j] = ss[it] * ap + cc[it] * aq;
            }
          }
        }
        __syncthreads();             // B2

        // column phase (+ eigenvector columns)
        if (full) {
          float ap[8], aq[8];
          #pragma unroll
          for (int it = 0; it < 8; ++it) {
            ap[it] = A[j * LD + pp[it]];
            aq[it] = A[j * LD + qq[it]];
          }
          #pragma unroll
          for (int it = 0; it < 8; ++it) {
            A[j * LD + pp[it]] = cc[it] * ap[it] - ss[it] * aq[it];
            A[j * LD + qq[it]] = ss[it] * ap[it] + cc[it] * aq[it];
          }
          if (WITH_V) {
            float vp[8], vq[8];
            #pragma unroll
            for (int it = 0; it < 8; ++it) {
              vp[it] = V[j * LD + pp[it]];
              vq[it] = V[j * LD + qq[it]];
            }
            #pragma unroll
            for (int it = 0; it < 8; ++it) {
              V[j * LD + pp[it]] = cc[it] * vp[it] - ss[it] * vq[it];
              V[j * LD + qq[it]] = ss[it] * vp[it] + cc[it] * vq[it];
            }
          }
        } else {
          #pragma unroll
          for (int it = 0; it < 8; ++it) {
            if ((m >> (wv + (it << 2))) & 1u) {
              float ap = A[j * LD + pp[it]], aq = A[j * LD + qq[it]];
              A[j * LD + pp[it]] = cc[it] * ap - ss[it] * aq;
              A[j * LD + qq[it]] = ss[it] * ap + cc[it] * aq;
              if (WITH_V) {
                float vp = V[j * LD + pp[it]], vq = V[j * LD + qq[it]];
                V[j * LD + pp[it]] = cc[it] * vp - ss[it] * vq;
                V[j * LD + qq[it]] = ss[it] * vp + cc[it] * vq;
              }
            }
          }
        }
        __syncthreads();             // B3
      }
      // empty round: only B1 needed (A untouched; csb/flgs double-buffered)
    }
    if (!anyrot) break;
  }
  __syncthreads();
}

// O = Lg @ S ; Lg global row-major 64 (wave-uniform scalar loads), S LDS (ld 65).
// Lane-distinct LDS reads: 64 per thread. No alias O/S.
__device__ void gemm_gS(const float* __restrict__ Lg, const float* S, float* O)
{
  const int tid = threadIdx.x;
  const int j  = tid & 63;
  const int iw = __builtin_amdgcn_readfirstlane((tid >> 6) << 4);
  float acc[16];
  #pragma unroll
  for (int ii = 0; ii < 16; ++ii) acc[ii] = 0.0f;
  for (int kb = 0; kb < 64; kb += 4) {
    float sv0 = S[(kb + 0) * LD + j];
    float sv1 = S[(kb + 1) * LD + j];
    float sv2 = S[(kb + 2) * LD + j];
    float sv3 = S[(kb + 3) * LD + j];
    #pragma unroll
    for (int ii = 0; ii < 16; ++ii) {
      const float* lr = Lg + (iw + ii) * 64 + kb;   // wave-uniform -> s_load
      acc[ii] += lr[0] * sv0 + lr[1] * sv1 + lr[2] * sv2 + lr[3] * sv3;
    }
  }
  #pragma unroll
  for (int ii = 0; ii < 16; ++ii) O[(iw + ii) * LD + j] = acc[ii];
}

// O = S @ Rg with Rg SYMMETRIC global (accessed by rows, wave-uniform scalar):
// O[i][j] = sum_k S[i][k]*Rg[j*64+k]
__device__ void gemm_SgT(const float* S, const float* __restrict__ Rg, float* O)
{
  const int tid = threadIdx.x;
  const int i  = tid & 63;
  const int jw = __builtin_amdgcn_readfirstlane((tid >> 6) << 4);
  float acc[16];
  #pragma unroll
  for (int jj = 0; jj < 16; ++jj) acc[jj] = 0.0f;
  for (int kb = 0; kb < 64; kb += 4) {
    float s0 = S[i * LD + kb + 0];
    float s1 = S[i * LD + kb + 1];
    float s2 = S[i * LD + kb + 2];
    float s3 = S[i * LD + kb + 3];
    #pragma unroll
    for (int jj = 0; jj < 16; ++jj) {
      const float* rr = Rg + (jw + jj) * 64 + kb;   // wave-uniform -> s_load
      acc[jj] += s0 * rr[0] + s1 * rr[1] + s2 * rr[2] + s3 * rr[3];
    }
  }
  #pragma unroll
  for (int jj = 0; jj < 16; ++jj) O[i * LD + jw + jj] = acc[jj];
}

// O[i][j] = sum_k P[i][k] * w[k] * V[j][k]  (all LDS). O may alias V or P
// (register-staged; internal barrier before the store).
__device__ void gemm_ADT(const float* P, const float* w, const float* V, float* O)
{
  const int tid = threadIdx.x;
  const int i  = tid & 63;
  const int jw = __builtin_amdgcn_readfirstlane((tid >> 6) << 4);
  float acc[16];
  #pragma unroll
  for (int jj = 0; jj < 16; ++jj) acc[jj] = 0.0f;
  for (int k = 0; k < 64; ++k) {
    float pw = P[i * LD + k] * w[k];
    #pragma unroll
    for (int jj = 0; jj < 16; ++jj) acc[jj] += pw * V[(jw + jj) * LD + k];
  }
  __syncthreads();
  #pragma unroll
  for (int jj = 0; jj < 16; ++jj) O[i * LD + jw + jj] = acc[jj];
}

// --- prep: eigh(ref + eps I) -> rm = ref^{-1/2}, rp = ref^{1/2}; zero queue ---
__global__ __launch_bounds__(BLOCK) void vae_prep(const float* __restrict__ ref,
                                                  float* __restrict__ rmrp)
{
  __shared__ __align__(16) float sA[NN * LD];
  __shared__ __align__(16) float sT[NN * LD];
  __shared__ float red[BLOCK];
  __shared__ float wb[64];
  __shared__ float2 csb[2 * NPAIR];
  __shared__ unsigned flgs[2];
  const int tid = threadIdx.x;

  if (tid == 0) ((unsigned*)rmrp)[8192] = 0u;   // work-queue counter

  for (int idx = tid; idx < NN * NN; idx += BLOCK) {
    int i = idx >> 6, j = idx & 63;
    sA[i * LD + j] = ref[idx] + ((i == j) ? EPSF : 0.0f);
  }
  __syncthreads();
  jacobi64<true>(sA, sT, csb, flgs, red, RELTOL_FULL);
  if (tid < 64) wb[tid] = sA[tid * LD + tid];
  __syncthreads();

  const int i  = tid & 63;
  const int jw = (tid >> 6) << 4;
  float am[16], aps[16];
  #pragma unroll
  for (int jj = 0; jj < 16; ++jj) { am[jj] = 0.0f; aps[jj] = 0.0f; }
  for (int k = 0; k < 64; ++k) {
    float vik = sT[i * LD + k];
    float wk  = wb[k];
    float rs  = 1.0f / sqrtf(wk);   // ref SPD: wk >= ~0.5
    float sq  = sqrtf(wk);
    float pr = vik * rs, pq = vik * sq;
    #pragma unroll
    for (int jj = 0; jj < 16; ++jj) {
      float vjk = sT[(jw + jj) * LD + k];
      am[jj]  += pr * vjk;
      aps[jj] += pq * vjk;
    }
  }
  #pragma unroll
  for (int jj = 0; jj < 16; ++jj) {
    rmrp[i * 64 + jw + jj]        = am[jj];
    rmrp[4096 + i * 64 + jw + jj] = aps[jj];
  }
}

// --- main: persistent blocks + atomic work queue, fully fused per item ---
__global__ __launch_bounds__(BLOCK, 4) void vae_main(
    const float* __restrict__ x,   const float* __restrict__ ref,
    float* __restrict__ rmrp,
    const float* __restrict__ w1,  const float* __restrict__ b1,
    const float* __restrict__ g1,  const float* __restrict__ bb1,
    const float* __restrict__ w2,  const float* __restrict__ b2,
    const float* __restrict__ g2,  const float* __restrict__ bb2,
    const float* __restrict__ muw, const float* __restrict__ mub,
    const float* __restrict__ lvw, const float* __restrict__ lvb,
    const float* __restrict__ dw1, const float* __restrict__ db1,
    const float* __restrict__ dg1, const float* __restrict__ dbb1,
    const float* __restrict__ dw2, const float* __restrict__ db2,
    const float* __restrict__ dg2, const float* __restrict__ dbb2,
    const float* __restrict__ dw3, const float* __restrict__ db3,
    float* __restrict__ out)
{
  __shared__ __align__(16) float sA[NN * LD];
  __shared__ __align__(16) float sT[NN * LD];   // also hosts svec (2080 <= 4160)
  __shared__ float red[BLOCK];
  __shared__ float h1s[128], h2s[64], zs[32], d1s[64], d2s[128];
  __shared__ float wb[64];
  __shared__ float2 csb[2 * NPAIR];
  __shared__ unsigned flgs[2];
  __shared__ float shiftv;
  __shared__ int curItem;

  const int tid = threadIdx.x;
  const float* rm = rmrp;
  const float* rp = rmrp + 4096;
  unsigned* qc = (unsigned*)rmrp + 8192;
  float* svec = sT;   // alias: sT is dead during the MLP phase

  for (;;) {
    if (tid == 0) curItem = (int)atomicAdd(qc, 1u);
    __syncthreads();
    const int b = curItem;
    if (b >= BATCH) break;

    // load x (shift for _ensure_spd(x) is provably 0: lambda_min(x) >= 0.5)
    for (int idx = tid; idx < 4096; idx += BLOCK)
      sA[(idx >> 6) * LD + (idx & 63)] = x[b * 4096 + idx];
    __syncthreads();

    gemm_gS(rm, sA, sT);            // T = rm @ x
    __syncthreads();
    gemm_SgT(sT, rm, sA);           // A = T @ rm = s
    __syncthreads();

    jacobi64<true>(sA, sT, csb, flgs, red, RELTOL_FULL);  // s = V w V^T
    if (tid < 64) wb[tid] = logf(fmaxf(sA[tid * LD + tid], 1e-12f));
    __syncthreads();

    gemm_gS(rm, sT, sA);            // A = rm @ V
    __syncthreads();
    gemm_ADT(sA, wb, sT, sT);       // T = (rm V) diag(log w) V^T  (alias-safe)
    __syncthreads();
    gemm_SgT(sT, rp, sA);           // A = tang = T @ rp
    __syncthreads();

    // vec = upper-triangle of tang (row-major triu order) -> svec (in sT)
    for (int idx = tid; idx < TRI; idx += BLOCK) {
      int i = (int)((129.0f - sqrtf(16641.0f - 8.0f * (float)idx)) * 0.5f);
      while (triOff(i + 1) <= idx) ++i;
      while (triOff(i) > idx) --i;
      int jj = i + (idx - triOff(i));
      red[0] = red[0];  // no-op
      svec[idx] = sA[i * LD + jj];
    }
    __syncthreads();

    // encoder L1: 2080 -> 128
    {
      int o = tid & 127, half = tid >> 7;
      const float4* wr = (const float4*)(w1 + o * 2080 + half * 1040);
      const float4* vv = (const float4*)(svec + half * 1040);
      float acc = 0.0f;
      for (int i4 = 0; i4 < 260; ++i4) {
        float4 a = wr[i4], v4 = vv[i4];
        acc += a.x * v4.x + a.y * v4.y + a.z * v4.z + a.w * v4.w;
      }
      red[tid] = acc;
      __syncthreads();
      if (tid < 128)
        h1s[tid] = bn_leaky(red[tid] + red[tid + 128] + b1[tid], g1[tid], bb1[tid]);
      __syncthreads();
    }
    // encoder L2: 128 -> 64
    {
      int o = tid & 63, half = tid >> 6;
      const float* wr = w2 + o * 128 + half * 32;
      const float* hh = h1s + half * 32;
      float acc = 0.0f;
      #pragma unroll 8
      for (int i = 0; i < 32; ++i) acc += wr[i] * hh[i];
      red[tid] = acc;
      __syncthreads();
      if (tid < 64)
        h2s[tid] = bn_leaky(red[tid] + red[tid + 64] + red[tid + 128] + red[tid + 192] + b2[tid],
                            g2[tid], bb2[tid]);
      __syncthreads();
    }
    // mu / logvar: 64 -> 32 each (z = mu)
    if (tid < 64) {
      int o = tid & 31;
      const float* wr = (tid < 32 ? muw : lvw) + o * 64;
      float acc = (tid < 32 ? mub : lvb)[o];
      for (int i = 0; i < 64; ++i) acc += wr[i] * h2s[i];
      if (tid < 32) { zs[o] = acc; out[MU_OFF + b * 32 + o] = acc; }
      else          { out[LV_OFF + b * 32 + o] = acc; }
    }
    __syncthreads();
    // decoder L1: 32 -> 64
    if (tid < 64) {
      const float* wr = dw1 + tid * 32;
      float acc = db1[tid];
      for (int i = 0; i < 32; ++i) acc += wr[i] * zs[i];
      d1s[tid] = bn_leaky(acc, dg1[tid], dbb1[tid]);
    }
    __syncthreads();
    // decoder L2: 64 -> 128
    if (tid < 128) {
      const float* wr = dw2 + tid * 64;
      float acc = db2[tid];
      for (int i = 0; i < 64; ++i) acc += wr[i] * d1s[i];
      d2s[tid] = bn_leaky(acc, dg2[tid], dbb2[tid]);
    }
    __syncthreads();
    // decoder L3: 128 -> 2080 (vdec into svec)
    for (int o = tid; o < TRI; o += BLOCK) {
      const float4* wr = (const float4*)(dw3 + o * 128);
      float acc = db3[o];
      #pragma unroll 8
      for (int k4 = 0; k4 < 32; ++k4) {
        float4 a = wr[k4];
        acc += a.x * d2s[k4 * 4] + a.y * d2s[k4 * 4 + 1] + a.z * d2s[k4 * 4 + 2] + a.w * d2s[k4 * 4 + 3];
      }
      svec[o] = acc;
    }
    __syncthreads();

    // m (symmetric from vdec) + eps I
    for (int idx = tid; idx < 4096; idx += BLOCK) {
      int i = idx >> 6, jj = idx & 63;
      int lo = (i < jj) ? i : jj, hi = (i < jj) ? jj : i;
      sA[i * LD + jj] = svec[triOff(lo) + (hi - lo)] + ((i == jj) ? EPSF : 0.0f);
    }
    __syncthreads();

    jacobi64<true>(sA, sT, csb, flgs, red, RELTOL_FULL);  // m = V w V^T (kills svec)
    if (tid < 64) wb[tid] = expf(sA[tid * LD + tid]);
    __syncthreads();
    gemm_ADT(sT, wb, sT, sA);       // A = exp_a = V diag(e^w) V^T
    __syncthreads();
    gemm_gS(ref, sA, sT);           // T = M2 = ref @ exp_a
    __syncthreads();

    // sym_lower(M2) -> A ; eigenvalues-only for the SPD shift
    for (int idx = tid; idx < 4096; idx += BLOCK) {
      int i = idx >> 6, jj = idx & 63;
      sA[i * LD + jj] = (i >= jj) ? sT[i * LD + jj] : sT[jj * LD + i];
    }
    __syncthreads();
    jacobi64<false>(sA, nullptr, csb, flgs, red, RELTOL_VALS);
    if (tid == 0) {
      float mn = sA[0];
      for (int i = 1; i < 64; ++i) mn = fminf(mn, sA[i * LD + i]);
      shiftv = fmaxf(EPSF - mn, 0.0f);
    }
    __syncthreads();

    const float sh = shiftv;
    for (int idx = tid; idx < 4096; idx += BLOCK) {
      int i = idx >> 6, jj = idx & 63;
      out[b * 4096 + idx] = sT[i * LD + jj] + ((i == jj) ? sh : 0.0f);
    }
    __syncthreads();   // protect shared reuse + curItem rewrite next iteration
  }
}

extern "C" void kernel_launch(void* const* d_in, const int* in_sizes, int n_in,
                              void* d_out, int out_size, void* d_ws, size_t ws_size,
                              hipStream_t stream) {
  (void)in_sizes; (void)n_in; (void)out_size; (void)ws_size;
  const float* x    = (const float*)d_in[0];
  const float* ref  = (const float*)d_in[1];
  const float* w1   = (const float*)d_in[2];
  const float* b1   = (const float*)d_in[3];
  const float* g1   = (const float*)d_in[4];
  const float* bb1  = (const float*)d_in[5];
  const float* w2   = (const float*)d_in[6];
  const float* b2   = (const float*)d_in[7];
  const float* g2   = (const float*)d_in[8];
  const float* bb2  = (const float*)d_in[9];
  const float* muw  = (const float*)d_in[10];
  const float* mub  = (const float*)d_in[11];
  const float* lvw  = (const float*)d_in[12];
  const float* lvb  = (const float*)d_in[13];
  const float* dw1  = (const float*)d_in[14];
  const float* db1  = (const float*)d_in[15];
  const float* dg1  = (const float*)d_in[16];
  const float* dbb1 = (const float*)d_in[17];
  const float* dw2  = (const float*)d_in[18];
  const float* db2  = (const float*)d_in[19];
  const float* dg2  = (const float*)d_in[20];
  const float* dbb2 = (const float*)d_in[21];
  const float* dw3  = (const float*)d_in[22];
  const float* db3  = (const float*)d_in[23];
  float* out = (float*)d_out;
  float* ws  = (float*)d_ws;   // rm (4096) + rp (4096) + queue counter (1 uint)

  vae_prep<<<1, BLOCK, 0, stream>>>(ref, ws);
  vae_main<<<GRID_MAIN, BLOCK, 0, stream>>>(x, ref, ws,
      w1, b1, g1, bb1, w2, b2, g2, bb2, muw, mub, lvw, lvb,
      dw1, db1, dg1, dbb1, dw2, db2, dg2, dbb2, dw3, db3, out);
}

// Round 3
// 17690.988 us; speedup vs baseline: 1.4006x; 1.4006x over previous
//
#include <hip/hip_runtime.h>

#define NN 64
#define LD 65
#define NPAIR 32
#define BLOCK 256
#define MAXSWEEP 11
#define EPSF 1e-6f
#define TRI 2080
#define BATCH 4096
#define MU_OFF 16777216
#define LV_OFF 16908288
#define RELTOL_FULL 1e-10f
#define RELTOL_VALS 1e-8f

__device__ __forceinline__ int triOff(int i) { return (i * (129 - i)) >> 1; }

__device__ __forceinline__ float bn_leaky(float h, float g, float bb) {
  h = (h >= 0.0f) ? h : 0.2f * h;
  return h * (1.0f / sqrtf(1.0f + 1e-5f)) * g + bb;
}

// Parallel cyclic Jacobi eigensolver for a 64x64 symmetric matrix in LDS (ld=65).
// Round-1 structure (single path, no ballot — keeps VGPR pressure low, no spills).
// On exit: diag(A) = eigenvalues (unsorted), V = eigenvectors (columns), if WITH_V.
template<bool WITH_V>
__device__ void jacobi64(float* A, float* V, float* cb, float* sb, int* pb, int* qb,
                         float* red, float relTol)
{
  const int tid = threadIdx.x;
  const int wv  = tid >> 6;   // wave id 0..3
  const int j   = tid & 63;

  if (WITH_V) {
    for (int idx = tid; idx < NN * LD; idx += BLOCK) V[idx] = 0.0f;
    __syncthreads();
    if (tid < NN) V[tid * LD + tid] = 1.0f;
  }

  // Frobenius^2 (rotation invariant) -> convergence reference
  float fp = 0.0f;
  for (int idx = tid; idx < NN * NN; idx += BLOCK) {
    float a = A[(idx >> 6) * LD + (idx & 63)];
    fp += a * a;
  }
  red[tid] = fp;
  __syncthreads();
  for (int s2 = BLOCK / 2; s2 > 0; s2 >>= 1) {
    if (tid < s2) red[tid] += red[tid + s2];
    __syncthreads();
  }
  const float tol = red[0] * relTol + 1e-30f;
  __syncthreads();

  for (int sweep = 0; sweep < MAXSWEEP; ++sweep) {
    // off-diagonal norm^2
    float op = 0.0f;
    for (int idx = tid; idx < NN * NN; idx += BLOCK) {
      int i2 = idx >> 6, j2 = idx & 63;
      if (i2 != j2) { float a = A[i2 * LD + j2]; op += a * a; }
    }
    red[tid] = op;
    __syncthreads();
    for (int s2 = BLOCK / 2; s2 > 0; s2 >>= 1) {
      if (tid < s2) red[tid] += red[tid + s2];
      __syncthreads();
    }
    float off2 = red[0];
    __syncthreads();
    if (off2 <= tol) break;

    for (int r = 0; r < 63; ++r) {
      // rotation angles for the 32 disjoint pairs of this round
      if (tid < NPAIR) {
        int p, q;
        if (tid == 0) { p = 63; q = r; }
        else { p = (r + tid) % 63; q = (r + 63 - tid) % 63; }
        if (p > q) { int t = p; p = q; q = t; }
        float app = A[p * LD + p], aqq = A[q * LD + q], apq = A[p * LD + q];
        float c = 1.0f, s = 0.0f;
        if (fabsf(apq) > 1e-36f) {
          float th = (aqq - app) / (2.0f * apq);
          float t = 1.0f / (fabsf(th) + sqrtf(th * th + 1.0f));
          if (th < 0.0f) t = -t;
          c = 1.0f / sqrtf(t * t + 1.0f);
          s = t * c;
        }
        cb[tid] = c; sb[tid] = s; pb[tid] = p; qb[tid] = q;
      }
      __syncthreads();

      float cc[8], ss[8]; int pp[8], qq[8];
      #pragma unroll
      for (int it = 0; it < 8; ++it) {
        int kk = wv + (it << 2);
        cc[it] = cb[kk]; ss[it] = sb[kk]; pp[it] = pb[kk]; qq[it] = qb[kk];
      }

      // row phase: rows p,q of each pair, all columns j (reads first, then writes)
      float ap[8], aq[8];
      #pragma unroll
      for (int it = 0; it < 8; ++it) {
        ap[it] = A[pp[it] * LD + j];
        aq[it] = A[qq[it] * LD + j];
      }
      #pragma unroll
      for (int it = 0; it < 8; ++it) {
        A[pp[it] * LD + j] = cc[it] * ap[it] - ss[it] * aq[it];
        A[qq[it] * LD + j] = ss[it] * ap[it] + cc[it] * aq[it];
      }
      __syncthreads();

      // column phase (+ eigenvector columns)
      #pragma unroll
      for (int it = 0; it < 8; ++it) {
        ap[it] = A[j * LD + pp[it]];
        aq[it] = A[j * LD + qq[it]];
      }
      #pragma unroll
      for (int it = 0; it < 8; ++it) {
        A[j * LD + pp[it]] = cc[it] * ap[it] - ss[it] * aq[it];
        A[j * LD + qq[it]] = ss[it] * ap[it] + cc[it] * aq[it];
      }
      if (WITH_V) {
        float vp[8], vq[8];
        #pragma unroll
        for (int it = 0; it < 8; ++it) {
          vp[it] = V[j * LD + pp[it]];
          vq[it] = V[j * LD + qq[it]];
        }
        #pragma unroll
        for (int it = 0; it < 8; ++it) {
          V[j * LD + pp[it]] = cc[it] * vp[it] - ss[it] * vq[it];
          V[j * LD + qq[it]] = ss[it] * vp[it] + cc[it] * vq[it];
        }
      }
      __syncthreads();
    }
  }
  __syncthreads();
}

// O = Lg @ S ; Lg global row-major 64 (wave-uniform scalar loads), S LDS (ld 65).
// Lane-distinct LDS reads: 64 per thread. No alias O/S.
__device__ void gemm_gS(const float* __restrict__ Lg, const float* S, float* O)
{
  const int tid = threadIdx.x;
  const int j  = tid & 63;
  const int iw = __builtin_amdgcn_readfirstlane((tid >> 6) << 4);
  float acc[16];
  #pragma unroll
  for (int ii = 0; ii < 16; ++ii) acc[ii] = 0.0f;
  for (int kb = 0; kb < 64; kb += 4) {
    float sv0 = S[(kb + 0) * LD + j];
    float sv1 = S[(kb + 1) * LD + j];
    float sv2 = S[(kb + 2) * LD + j];
    float sv3 = S[(kb + 3) * LD + j];
    #pragma unroll
    for (int ii = 0; ii < 16; ++ii) {
      const float* lr = Lg + (iw + ii) * 64 + kb;   // wave-uniform -> s_load
      acc[ii] += lr[0] * sv0 + lr[1] * sv1 + lr[2] * sv2 + lr[3] * sv3;
    }
  }
  #pragma unroll
  for (int ii = 0; ii < 16; ++ii) O[(iw + ii) * LD + j] = acc[ii];
}

// O = S @ Rg with Rg SYMMETRIC global (accessed by rows, wave-uniform scalar):
// O[i][j] = sum_k S[i][k]*Rg[j*64+k]
__device__ void gemm_SgT(const float* S, const float* __restrict__ Rg, float* O)
{
  const int tid = threadIdx.x;
  const int i  = tid & 63;
  const int jw = __builtin_amdgcn_readfirstlane((tid >> 6) << 4);
  float acc[16];
  #pragma unroll
  for (int jj = 0; jj < 16; ++jj) acc[jj] = 0.0f;
  for (int kb = 0; kb < 64; kb += 4) {
    float s0 = S[i * LD + kb + 0];
    float s1 = S[i * LD + kb + 1];
    float s2 = S[i * LD + kb + 2];
    float s3 = S[i * LD + kb + 3];
    #pragma unroll
    for (int jj = 0; jj < 16; ++jj) {
      const float* rr = Rg + (jw + jj) * 64 + kb;   // wave-uniform -> s_load
      acc[jj] += s0 * rr[0] + s1 * rr[1] + s2 * rr[2] + s3 * rr[3];
    }
  }
  #pragma unroll
  for (int jj = 0; jj < 16; ++jj) O[i * LD + jw + jj] = acc[jj];
}

// O[i][j] = sum_k P[i][k] * w[k] * V[j][k]  (all LDS). O may alias V or P
// (register-staged; internal barrier before the store).
__device__ void gemm_ADT(const float* P, const float* w, const float* V, float* O)
{
  const int tid = threadIdx.x;
  const int i  = tid & 63;
  const int jw = __builtin_amdgcn_readfirstlane((tid >> 6) << 4);
  float acc[16];
  #pragma unroll
  for (int jj = 0; jj < 16; ++jj) acc[jj] = 0.0f;
  for (int k = 0; k < 64; ++k) {
    float pw = P[i * LD + k] * w[k];
    #pragma unroll
    for (int jj = 0; jj < 16; ++jj) acc[jj] += pw * V[(jw + jj) * LD + k];
  }
  __syncthreads();
  #pragma unroll
  for (int jj = 0; jj < 16; ++jj) O[i * LD + jw + jj] = acc[jj];
}

// --- prep: eigh(ref + eps I) -> rm = ref^{-1/2}, rp = ref^{1/2} into ws ---
__global__ __launch_bounds__(BLOCK) void vae_prep(const float* __restrict__ ref,
                                                  float* __restrict__ rmrp)
{
  __shared__ __align__(16) float sA[NN * LD];
  __shared__ __align__(16) float sT[NN * LD];
  __shared__ float red[BLOCK];
  __shared__ float wb[64];
  __shared__ float cb[NPAIR], sb[NPAIR];
  __shared__ int   pb[NPAIR], qb[NPAIR];
  const int tid = threadIdx.x;

  for (int idx = tid; idx < NN * NN; idx += BLOCK) {
    int i = idx >> 6, j = idx & 63;
    sA[i * LD + j] = ref[idx] + ((i == j) ? EPSF : 0.0f);
  }
  __syncthreads();
  jacobi64<true>(sA, sT, cb, sb, pb, qb, red, RELTOL_FULL);
  if (tid < 64) wb[tid] = sA[tid * LD + tid];
  __syncthreads();

  const int i  = tid & 63;
  const int jw = (tid >> 6) << 4;
  float am[16], aps[16];
  #pragma unroll
  for (int jj = 0; jj < 16; ++jj) { am[jj] = 0.0f; aps[jj] = 0.0f; }
  for (int k = 0; k < 64; ++k) {
    float vik = sT[i * LD + k];
    float wk  = wb[k];
    float rs  = 1.0f / sqrtf(wk);   // ref SPD: wk >= ~0.5
    float sq  = sqrtf(wk);
    float pr = vik * rs, pq = vik * sq;
    #pragma unroll
    for (int jj = 0; jj < 16; ++jj) {
      float vjk = sT[(jw + jj) * LD + k];
      am[jj]  += pr * vjk;
      aps[jj] += pq * vjk;
    }
  }
  #pragma unroll
  for (int jj = 0; jj < 16; ++jj) {
    rmrp[i * 64 + jw + jj]        = am[jj];
    rmrp[4096 + i * 64 + jw + jj] = aps[jj];
  }
}

// --- main: one block per batch item, fully fused ---
__global__ __launch_bounds__(BLOCK) void vae_main(
    const float* __restrict__ x,   const float* __restrict__ ref,
    const float* __restrict__ rmrp,
    const float* __restrict__ w1,  const float* __restrict__ b1,
    const float* __restrict__ g1,  const float* __restrict__ bb1,
    const float* __restrict__ w2,  const float* __restrict__ b2,
    const float* __restrict__ g2,  const float* __restrict__ bb2,
    const float* __restrict__ muw, const float* __restrict__ mub,
    const float* __restrict__ lvw, const float* __restrict__ lvb,
    const float* __restrict__ dw1, const float* __restrict__ db1,
    const float* __restrict__ dg1, const float* __restrict__ dbb1,
    const float* __restrict__ dw2, const float* __restrict__ db2,
    const float* __restrict__ dg2, const float* __restrict__ dbb2,
    const float* __restrict__ dw3, const float* __restrict__ db3,
    float* __restrict__ out)
{
  __shared__ __align__(16) float sA[NN * LD];
  __shared__ __align__(16) float sT[NN * LD];   // also hosts svec (2080 <= 4160)
  __shared__ float red[BLOCK];
  __shared__ float h1s[128], h2s[64], zs[32], d1s[64], d2s[128];
  __shared__ float wb[64];
  __shared__ float cb[NPAIR], sb[NPAIR];
  __shared__ int   pb[NPAIR], qb[NPAIR];
  __shared__ float shiftv;

  const int tid = threadIdx.x;
  const int b   = blockIdx.x;
  const float* rm = rmrp;
  const float* rp = rmrp + 4096;
  float* svec = sT;   // alias: sT is dead during the MLP phase

  // load x (shift for _ensure_spd(x) is provably 0: lambda_min(x) >= 0.5)
  for (int idx = tid; idx < 4096; idx += BLOCK)
    sA[(idx >> 6) * LD + (idx & 63)] = x[b * 4096 + idx];
  __syncthreads();

  gemm_gS(rm, sA, sT);            // T = rm @ x
  __syncthreads();
  gemm_SgT(sT, rm, sA);           // A = T @ rm = s
  __syncthreads();

  jacobi64<true>(sA, sT, cb, sb, pb, qb, red, RELTOL_FULL);  // s = V w V^T
  if (tid < 64) wb[tid] = logf(fmaxf(sA[tid * LD + tid], 1e-12f));
  __syncthreads();

  gemm_gS(rm, sT, sA);            // A = rm @ V
  __syncthreads();
  gemm_ADT(sA, wb, sT, sT);       // T = (rm V) diag(log w) V^T  (alias-safe)
  __syncthreads();
  gemm_SgT(sT, rp, sA);           // A = tang = T @ rp
  __syncthreads();

  // vec = upper-triangle of tang (row-major triu order) -> svec (in sT)
  for (int idx = tid; idx < TRI; idx += BLOCK) {
    int i = (int)((129.0f - sqrtf(16641.0f - 8.0f * (float)idx)) * 0.5f);
    while (triOff(i + 1) <= idx) ++i;
    while (triOff(i) > idx) --i;
    int jj = i + (idx - triOff(i));
    svec[idx] = sA[i * LD + jj];
  }
  __syncthreads();

  // encoder L1: 2080 -> 128
  {
    int o = tid & 127, half = tid >> 7;
    const float4* wr = (const float4*)(w1 + o * 2080 + half * 1040);
    const float4* vv = (const float4*)(svec + half * 1040);
    float acc = 0.0f;
    for (int i4 = 0; i4 < 260; ++i4) {
      float4 a = wr[i4], v4 = vv[i4];
      acc += a.x * v4.x + a.y * v4.y + a.z * v4.z + a.w * v4.w;
    }
    red[tid] = acc;
    __syncthreads();
    if (tid < 128)
      h1s[tid] = bn_leaky(red[tid] + red[tid + 128] + b1[tid], g1[tid], bb1[tid]);
    __syncthreads();
  }
  // encoder L2: 128 -> 64
  {
    int o = tid & 63, half = tid >> 6;
    const float* wr = w2 + o * 128 + half * 32;
    const float* hh = h1s + half * 32;
    float acc = 0.0f;
    #pragma unroll 8
    for (int i = 0; i < 32; ++i) acc += wr[i] * hh[i];
    red[tid] = acc;
    __syncthreads();
    if (tid < 64)
      h2s[tid] = bn_leaky(red[tid] + red[tid + 64] + red[tid + 128] + red[tid + 192] + b2[tid],
                          g2[tid], bb2[tid]);
    __syncthreads();
  }
  // mu / logvar: 64 -> 32 each (z = mu)
  if (tid < 64) {
    int o = tid & 31;
    const float* wr = (tid < 32 ? muw : lvw) + o * 64;
    float acc = (tid < 32 ? mub : lvb)[o];
    for (int i = 0; i < 64; ++i) acc += wr[i] * h2s[i];
    if (tid < 32) { zs[o] = acc; out[MU_OFF + b * 32 + o] = acc; }
    else          { out[LV_OFF + b * 32 + o] = acc; }
  }
  __syncthreads();
  // decoder L1: 32 -> 64
  if (tid < 64) {
    const float* wr = dw1 + tid * 32;
    float acc = db1[tid];
    for (int i = 0; i < 32; ++i) acc += wr[i] * zs[i];
    d1s[tid] = bn_leaky(acc, dg1[tid], dbb1[tid]);
  }
  __syncthreads();
  // decoder L2: 64 -> 128
  if (tid < 128) {
    const float* wr = dw2 + tid * 64;
    float acc = db2[tid];
    for (int i = 0; i < 64; ++i) acc += wr[i] * d1s[i];
    d2s[tid] = bn_leaky(acc, dg2[tid], dbb2[tid]);
  }
  __syncthreads();
  // decoder L3: 128 -> 2080 (vdec into svec)
  for (int o = tid; o < TRI; o += BLOCK) {
    const float4* wr = (const float4*)(dw3 + o * 128);
    float acc = db3[o];
    #pragma unroll 8
    for (int k4 = 0; k4 < 32; ++k4) {
      float4 a = wr[k4];
      acc += a.x * d2s[k4 * 4] + a.y * d2s[k4 * 4 + 1] + a.z * d2s[k4 * 4 + 2] + a.w * d2s[k4 * 4 + 3];
    }
    svec[o] = acc;
  }
  __syncthreads();

  // m (symmetric from vdec) + eps I
  for (int idx = tid; idx < 4096; idx += BLOCK) {
    int i = idx >> 6, jj = idx & 63;
    int lo = (i < jj) ? i : jj, hi = (i < jj) ? jj : i;
    sA[i * LD + jj] = svec[triOff(lo) + (hi - lo)] + ((i == jj) ? EPSF : 0.0f);
  }
  __syncthreads();

  jacobi64<true>(sA, sT, cb, sb, pb, qb, red, RELTOL_FULL);  // m = V w V^T
  if (tid < 64) wb[tid] = expf(sA[tid * LD + tid]);
  __syncthreads();
  gemm_ADT(sT, wb, sT, sA);       // A = exp_a = V diag(e^w) V^T
  __syncthreads();
  gemm_gS(ref, sA, sT);           // T = M2 = ref @ exp_a
  __syncthreads();

  // --- SPD shift for recon = M2 + shift*I, shift = max(EPS - lambda_min(sym_lower(M2)), 0)
  // Fast path: LDL^T PD-test of C = sym_lower(M2) - EPS*I. All pivots > 0 => shift = 0.
  {
    for (int idx = tid; idx < 4096; idx += BLOCK) {
      int i = idx >> 6, jj = idx & 63;
      float v = (i >= jj) ? sT[i * LD + jj] : sT[jj * LD + i];
      sA[i * LD + jj] = v - ((i == jj) ? EPSF : 0.0f);
    }
    __syncthreads();

    bool pd = true;
    const int col = tid & 63;
    const int rw  = tid >> 6;
    for (int k = 0; k < 64; ++k) {
      float d = sA[k * LD + k];          // broadcast; uniform across block
      if (d <= 1e-30f) { pd = false; break; }
      if (col > k) {
        float ljk = sA[col * LD + k] / d;   // column k: stride-LD, 2-way (free)
        for (int i = k + 1 + rw; i < 64; i += 4) {
          float aik = sA[i * LD + k];       // broadcast
          sA[i * LD + col] -= aik * ljk;    // row i contiguous: conflict-free
        }
      }
      __syncthreads();
    }

    if (pd) {
      if (tid == 0) shiftv = 0.0f;
      __syncthreads();
    } else {
      __syncthreads();  // re-converge (break is uniform, but be explicit)
      // Fallback: eigenvalues-only Jacobi on sym_lower(M2)
      for (int idx = tid; idx < 4096; idx += BLOCK) {
        int i = idx >> 6, jj = idx & 63;
        sA[i * LD + jj] = (i >= jj) ? sT[i * LD + jj] : sT[jj * LD + i];
      }
      __syncthreads();
      jacobi64<false>(sA, nullptr, cb, sb, pb, qb, red, RELTOL_VALS);
      if (tid == 0) {
        float mn = sA[0];
        for (int i = 1; i < 64; ++i) mn = fminf(mn, sA[i * LD + i]);
        shiftv = fmaxf(EPSF - mn, 0.0f);
      }
      __syncthreads();
    }
  }

  const float sh = shiftv;
  for (int idx = tid; idx < 4096; idx += BLOCK) {
    int i = idx >> 6, jj = idx & 63;
    out[b * 4096 + idx] = sT[i * LD + jj] + ((i == jj) ? sh : 0.0f);
  }
}

extern "C" void kernel_launch(void* const* d_in, const int* in_sizes, int n_in,
                              void* d_out, int out_size, void* d_ws, size_t ws_size,
                              hipStream_t stream) {
  (void)in_sizes; (void)n_in; (void)out_size; (void)ws_size;
  const float* x    = (const float*)d_in[0];
  const float* ref  = (const float*)d_in[1];
  const float* w1   = (const float*)d_in[2];
  const float* b1   = (const float*)d_in[3];
  const float* g1   = (const float*)d_in[4];
  const float* bb1  = (const float*)d_in[5];
  const float* w2   = (const float*)d_in[6];
  const float* b2   = (const float*)d_in[7];
  const float* g2   = (const float*)d_in[8];
  const float* bb2  = (const float*)d_in[9];
  const float* muw  = (const float*)d_in[10];
  const float* mub  = (const float*)d_in[11];
  const float* lvw  = (const float*)d_in[12];
  const float* lvb  = (const float*)d_in[13];
  const float* dw1  = (const float*)d_in[14];
  const float* db1  = (const float*)d_in[15];
  const float* dg1  = (const float*)d_in[16];
  const float* dbb1 = (const float*)d_in[17];
  const float* dw2  = (const float*)d_in[18];
  const float* db2  = (const float*)d_in[19];
  const float* dg2  = (const float*)d_in[20];
  const float* dbb2 = (const float*)d_in[21];
  const float* dw3  = (const float*)d_in[22];
  const float* db3  = (const float*)d_in[23];
  float* out = (float*)d_out;
  float* ws  = (float*)d_ws;   // rm (4096 floats) + rp (4096 floats)

  vae_prep<<<1, BLOCK, 0, stream>>>(ref, ws);
  vae_main<<<BATCH, BLOCK, 0, stream>>>(x, ref, ws,
      w1, b1, g1, bb1, w2, b2, g2, bb2, muw, mub, lvw, lvb,
      dw1, db1, dg1, dbb1, dw2, db2, dg2, dbb2, dw3, db3, out);
}

// Round 4
// 10523.415 us; speedup vs baseline: 2.3545x; 1.6811x over previous
//
#include <hip/hip_runtime.h>

#define NN 64
#define LD 65
#define NPAIR 32
#define BLOCK 256
#define MAXSWEEP 11
#define EPSF 1e-6f
#define TRI 2080
#define BATCH 4096
#define MU_OFF 16777216
#define LV_OFF 16908288
#define RELTOL_MAIN 1e-8f
#define RELTOL_PREP 1e-12f
#define RELTOL_VALS 1e-8f

__device__ __forceinline__ int triOff(int i) { return (i * (129 - i)) >> 1; }

__device__ __forceinline__ float bn_leaky(float h, float g, float bb) {
  h = (h >= 0.0f) ? h : 0.2f * h;
  return h * (1.0f / sqrtf(1.0f + 1e-5f)) * g + bb;
}

// Parallel cyclic Jacobi eigensolver for a 64x64 symmetric matrix in LDS (ld=65).
// Pair indices computed arithmetically (no pb/qb LDS round-trip).
// On exit: diag(A) = eigenvalues (unsorted), V = eigenvectors (columns), if WITH_V.
template<bool WITH_V>
__device__ void jacobi64(float* A, float* V, float* cb, float* sb,
                         float* red, float relTol)
{
  const int tid = threadIdx.x;
  const int wv  = tid >> 6;   // wave id 0..3
  const int j   = tid & 63;

  if (WITH_V) {
    for (int idx = tid; idx < NN * LD; idx += BLOCK) V[idx] = 0.0f;
    __syncthreads();
    if (tid < NN) V[tid * LD + tid] = 1.0f;
  }

  // Frobenius^2 (rotation invariant) -> convergence reference
  float fp = 0.0f;
  for (int idx = tid; idx < NN * NN; idx += BLOCK) {
    float a = A[(idx >> 6) * LD + (idx & 63)];
    fp += a * a;
  }
  red[tid] = fp;
  __syncthreads();
  for (int s2 = BLOCK / 2; s2 > 0; s2 >>= 1) {
    if (tid < s2) red[tid] += red[tid + s2];
    __syncthreads();
  }
  const float tol = red[0] * relTol + 1e-30f;
  __syncthreads();

  for (int sweep = 0; sweep < MAXSWEEP; ++sweep) {
    // off-diagonal norm^2
    float op = 0.0f;
    for (int idx = tid; idx < NN * NN; idx += BLOCK) {
      int i2 = idx >> 6, j2 = idx & 63;
      if (i2 != j2) { float a = A[i2 * LD + j2]; op += a * a; }
    }
    red[tid] = op;
    __syncthreads();
    for (int s2 = BLOCK / 2; s2 > 0; s2 >>= 1) {
      if (tid < s2) red[tid] += red[tid + s2];
      __syncthreads();
    }
    float off2 = red[0];
    __syncthreads();
    if (off2 <= tol) break;

    for (int r = 0; r < 63; ++r) {
      // rotation angles for the 32 disjoint pairs of this round
      if (tid < NPAIR) {
        int p, q;
        if (tid == 0) { p = 63; q = r; }
        else {
          p = r + tid;      if (p >= 63) p -= 63;
          q = r + 63 - tid; if (q >= 63) q -= 63;
        }
        if (p > q) { int t = p; p = q; q = t; }
        float app = A[p * LD + p], aqq = A[q * LD + q], apq = A[p * LD + q];
        float c = 1.0f, s = 0.0f;
        if (fabsf(apq) > 1e-36f) {
          float th = (aqq - app) / (2.0f * apq);
          float t = 1.0f / (fabsf(th) + sqrtf(th * th + 1.0f));
          if (th < 0.0f) t = -t;
          c = 1.0f / sqrtf(t * t + 1.0f);
          s = t * c;
        }
        cb[tid] = c; sb[tid] = s;
      }
      __syncthreads();

      float cc[8], ss[8]; int pp[8], qq[8];
      #pragma unroll
      for (int it = 0; it < 8; ++it) {
        const int k = wv + (it << 2);
        cc[it] = cb[k]; ss[it] = sb[k];
        int p, q;
        if (k == 0) { p = 63; q = r; }
        else {
          p = r + k;      if (p >= 63) p -= 63;
          q = r + 63 - k; if (q >= 63) q -= 63;
        }
        if (p > q) { int t2 = p; p = q; q = t2; }
        pp[it] = p; qq[it] = q;
      }

      // row phase: rows p,q of each pair, all columns j (reads first, then writes)
      float ap[8], aq[8];
      #pragma unroll
      for (int it = 0; it < 8; ++it) {
        ap[it] = A[pp[it] * LD + j];
        aq[it] = A[qq[it] * LD + j];
      }
      #pragma unroll
      for (int it = 0; it < 8; ++it) {
        A[pp[it] * LD + j] = cc[it] * ap[it] - ss[it] * aq[it];
        A[qq[it] * LD + j] = ss[it] * ap[it] + cc[it] * aq[it];
      }
      __syncthreads();

      // column phase (+ eigenvector columns)
      #pragma unroll
      for (int it = 0; it < 8; ++it) {
        ap[it] = A[j * LD + pp[it]];
        aq[it] = A[j * LD + qq[it]];
      }
      #pragma unroll
      for (int it = 0; it < 8; ++it) {
        A[j * LD + pp[it]] = cc[it] * ap[it] - ss[it] * aq[it];
        A[j * LD + qq[it]] = ss[it] * ap[it] + cc[it] * aq[it];
      }
      if (WITH_V) {
        float vp[8], vq[8];
        #pragma unroll
        for (int it = 0; it < 8; ++it) {
          vp[it] = V[j * LD + pp[it]];
          vq[it] = V[j * LD + qq[it]];
        }
        #pragma unroll
        for (int it = 0; it < 8; ++it) {
          V[j * LD + pp[it]] = cc[it] * vp[it] - ss[it] * vq[it];
          V[j * LD + qq[it]] = ss[it] * vp[it] + cc[it] * vq[it];
        }
      }
      __syncthreads();
    }
  }
  __syncthreads();
}

// O = Lg @ S ; Lg global row-major 64 (wave-uniform scalar loads), S LDS (ld 65).
__device__ void gemm_gS(const float* __restrict__ Lg, const float* S, float* O)
{
  const int tid = threadIdx.x;
  const int j  = tid & 63;
  const int iw = __builtin_amdgcn_readfirstlane((tid >> 6) << 4);
  float acc[16];
  #pragma unroll
  for (int ii = 0; ii < 16; ++ii) acc[ii] = 0.0f;
  for (int kb = 0; kb < 64; kb += 4) {
    float sv0 = S[(kb + 0) * LD + j];
    float sv1 = S[(kb + 1) * LD + j];
    float sv2 = S[(kb + 2) * LD + j];
    float sv3 = S[(kb + 3) * LD + j];
    #pragma unroll
    for (int ii = 0; ii < 16; ++ii) {
      const float* lr = Lg + (iw + ii) * 64 + kb;   // wave-uniform -> s_load
      acc[ii] += lr[0] * sv0 + lr[1] * sv1 + lr[2] * sv2 + lr[3] * sv3;
    }
  }
  #pragma unroll
  for (int ii = 0; ii < 16; ++ii) O[(iw + ii) * LD + j] = acc[ii];
}

// O = S @ Rg with Rg SYMMETRIC global (rows, wave-uniform scalar):
// O[i][j] = sum_k S[i][k]*Rg[j*64+k]
__device__ void gemm_SgT(const float* S, const float* __restrict__ Rg, float* O)
{
  const int tid = threadIdx.x;
  const int i  = tid & 63;
  const int jw = __builtin_amdgcn_readfirstlane((tid >> 6) << 4);
  float acc[16];
  #pragma unroll
  for (int jj = 0; jj < 16; ++jj) acc[jj] = 0.0f;
  for (int kb = 0; kb < 64; kb += 4) {
    float s0 = S[i * LD + kb + 0];
    float s1 = S[i * LD + kb + 1];
    float s2 = S[i * LD + kb + 2];
    float s3 = S[i * LD + kb + 3];
    #pragma unroll
    for (int jj = 0; jj < 16; ++jj) {
      const float* rr = Rg + (jw + jj) * 64 + kb;   // wave-uniform -> s_load
      acc[jj] += s0 * rr[0] + s1 * rr[1] + s2 * rr[2] + s3 * rr[3];
    }
  }
  #pragma unroll
  for (int jj = 0; jj < 16; ++jj) O[i * LD + jw + jj] = acc[jj];
}

// O[i][j] = sum_k P[i][k] * w[k] * V[j][k]  (all LDS). O may alias V or P.
__device__ void gemm_ADT(const float* P, const float* w, const float* V, float* O)
{
  const int tid = threadIdx.x;
  const int i  = tid & 63;
  const int jw = __builtin_amdgcn_readfirstlane((tid >> 6) << 4);
  float acc[16];
  #pragma unroll
  for (int jj = 0; jj < 16; ++jj) acc[jj] = 0.0f;
  for (int k = 0; k < 64; ++k) {
    float pw = P[i * LD + k] * w[k];
    #pragma unroll
    for (int jj = 0; jj < 16; ++jj) acc[jj] += pw * V[(jw + jj) * LD + k];
  }
  __syncthreads();
  #pragma unroll
  for (int jj = 0; jj < 16; ++jj) O[i * LD + jw + jj] = acc[jj];
}

// --- prep: eigh(ref + eps I) -> rm = ref^{-1/2}, rp = ref^{1/2} into ws ---
__global__ __launch_bounds__(BLOCK) void vae_prep(const float* __restrict__ ref,
                                                  float* __restrict__ rmrp)
{
  __shared__ __align__(16) float sA[NN * LD];
  __shared__ __align__(16) float sT[NN * LD];
  __shared__ float red[BLOCK];
  __shared__ float wb[64];
  __shared__ float cb[NPAIR], sb[NPAIR];
  const int tid = threadIdx.x;

  for (int idx = tid; idx < NN * NN; idx += BLOCK) {
    int i = idx >> 6, j = idx & 63;
    sA[i * LD + j] = ref[idx] + ((i == j) ? EPSF : 0.0f);
  }
  __syncthreads();
  jacobi64<true>(sA, sT, cb, sb, red, RELTOL_PREP);
  if (tid < 64) wb[tid] = sA[tid * LD + tid];
  __syncthreads();

  const int i  = tid & 63;
  const int jw = (tid >> 6) << 4;
  float am[16], aps[16];
  #pragma unroll
  for (int jj = 0; jj < 16; ++jj) { am[jj] = 0.0f; aps[jj] = 0.0f; }
  for (int k = 0; k < 64; ++k) {
    float vik = sT[i * LD + k];
    float wk  = wb[k];
    float rs  = 1.0f / sqrtf(wk);   // ref SPD: wk >= ~0.5
    float sq  = sqrtf(wk);
    float pr = vik * rs, pq = vik * sq;
    #pragma unroll
    for (int jj = 0; jj < 16; ++jj) {
      float vjk = sT[(jw + jj) * LD + k];
      am[jj]  += pr * vjk;
      aps[jj] += pq * vjk;
    }
  }
  #pragma unroll
  for (int jj = 0; jj < 16; ++jj) {
    rmrp[i * 64 + jw + jj]        = am[jj];
    rmrp[4096 + i * 64 + jw + jj] = aps[jj];
  }
}

// --- main: one block per batch item, fully fused ---
__global__ __launch_bounds__(BLOCK) void vae_main(
    const float* __restrict__ x,   const float* __restrict__ ref,
    const float* __restrict__ rmrp,
    const float* __restrict__ w1,  const float* __restrict__ b1,
    const float* __restrict__ g1,  const float* __restrict__ bb1,
    const float* __restrict__ w2,  const float* __restrict__ b2,
    const float* __restrict__ g2,  const float* __restrict__ bb2,
    const float* __restrict__ muw, const float* __restrict__ mub,
    const float* __restrict__ lvw, const float* __restrict__ lvb,
    const float* __restrict__ dw1, const float* __restrict__ db1,
    const float* __restrict__ dg1, const float* __restrict__ dbb1,
    const float* __restrict__ dw2, const float* __restrict__ db2,
    const float* __restrict__ dg2, const float* __restrict__ dbb2,
    const float* __restrict__ dw3, const float* __restrict__ db3,
    float* __restrict__ out)
{
  __shared__ __align__(16) float sA[NN * LD];
  __shared__ __align__(16) float sT[NN * LD];   // also hosts svec (2080 <= 4160)
  __shared__ float red[BLOCK];
  __shared__ float h1s[128], h2s[64], zs[32], d1s[64], d2s[128];
  __shared__ float wb[64];
  __shared__ float cb[NPAIR], sb[NPAIR];
  __shared__ float shiftv;

  const int tid = threadIdx.x;
  const int b   = blockIdx.x;
  const float* rm = rmrp;
  const float* rp = rmrp + 4096;
  float* svec = sT;   // alias: sT is dead during the MLP phase

  // load x (shift for _ensure_spd(x) is provably 0: lambda_min(x) >= 0.5)
  for (int idx = tid; idx < 4096; idx += BLOCK)
    sA[(idx >> 6) * LD + (idx & 63)] = x[b * 4096 + idx];
  __syncthreads();

  gemm_gS(rm, sA, sT);            // T = rm @ x
  __syncthreads();
  gemm_SgT(sT, rm, sA);           // A = T @ rm = s
  __syncthreads();

  jacobi64<true>(sA, sT, cb, sb, red, RELTOL_MAIN);  // s = V w V^T (V in sT)
  if (tid < 64) wb[tid] = logf(fmaxf(sA[tid * LD + tid], 1e-12f));
  __syncthreads();

  gemm_gS(rm, sT, sA);            // A = rm @ V
  __syncthreads();
  gemm_ADT(sA, wb, sT, sT);       // T = (rm V) diag(log w) V^T  (alias-safe)
  __syncthreads();
  gemm_SgT(sT, rp, sA);           // A = tang = T @ rp
  __syncthreads();

  // vec = upper-triangle of tang (row-major triu order) -> svec (in sT)
  for (int idx = tid; idx < TRI; idx += BLOCK) {
    int i = (int)((129.0f - sqrtf(16641.0f - 8.0f * (float)idx)) * 0.5f);
    while (triOff(i + 1) <= idx) ++i;
    while (triOff(i) > idx) --i;
    int jj = i + (idx - triOff(i));
    svec[idx] = sA[i * LD + jj];
  }
  __syncthreads();

  // encoder L1: 2080 -> 128
  {
    int o = tid & 127, half = tid >> 7;
    const float4* wr = (const float4*)(w1 + o * 2080 + half * 1040);
    const float4* vv = (const float4*)(svec + half * 1040);
    float acc = 0.0f;
    for (int i4 = 0; i4 < 260; ++i4) {
      float4 a = wr[i4], v4 = vv[i4];
      acc += a.x * v4.x + a.y * v4.y + a.z * v4.z + a.w * v4.w;
    }
    red[tid] = acc;
    __syncthreads();
    if (tid < 128)
      h1s[tid] = bn_leaky(red[tid] + red[tid + 128] + b1[tid], g1[tid], bb1[tid]);
    __syncthreads();
  }
  // encoder L2: 128 -> 64
  {
    int o = tid & 63, half = tid >> 6;
    const float* wr = w2 + o * 128 + half * 32;
    const float* hh = h1s + half * 32;
    float acc = 0.0f;
    #pragma unroll 8
    for (int i = 0; i < 32; ++i) acc += wr[i] * hh[i];
    red[tid] = acc;
    __syncthreads();
    if (tid < 64)
      h2s[tid] = bn_leaky(red[tid] + red[tid + 64] + red[tid + 128] + red[tid + 192] + b2[tid],
                          g2[tid], bb2[tid]);
    __syncthreads();
  }
  // mu / logvar: 64 -> 32 each (z = mu)
  if (tid < 64) {
    int o = tid & 31;
    const float* wr = (tid < 32 ? muw : lvw) + o * 64;
    float acc = (tid < 32 ? mub : lvb)[o];
    for (int i = 0; i < 64; ++i) acc += wr[i] * h2s[i];
    if (tid < 32) { zs[o] = acc; out[MU_OFF + b * 32 + o] = acc; }
    else          { out[LV_OFF + b * 32 + o] = acc; }
  }
  __syncthreads();
  // decoder L1: 32 -> 64
  if (tid < 64) {
    const float* wr = dw1 + tid * 32;
    float acc = db1[tid];
    for (int i = 0; i < 32; ++i) acc += wr[i] * zs[i];
    d1s[tid] = bn_leaky(acc, dg1[tid], dbb1[tid]);
  }
  __syncthreads();
  // decoder L2: 64 -> 128
  if (tid < 128) {
    const float* wr = dw2 + tid * 64;
    float acc = db2[tid];
    for (int i = 0; i < 64; ++i) acc += wr[i] * d1s[i];
    d2s[tid] = bn_leaky(acc, dg2[tid], dbb2[tid]);
  }
  __syncthreads();
  // decoder L3: 128 -> 2080 (vdec into svec)
  for (int o = tid; o < TRI; o += BLOCK) {
    const float4* wr = (const float4*)(dw3 + o * 128);
    float acc = db3[o];
    #pragma unroll 8
    for (int k4 = 0; k4 < 32; ++k4) {
      float4 a = wr[k4];
      acc += a.x * d2s[k4 * 4] + a.y * d2s[k4 * 4 + 1] + a.z * d2s[k4 * 4 + 2] + a.w * d2s[k4 * 4 + 3];
    }
    svec[o] = acc;
  }
  __syncthreads();

  // mtil = symmetric(vdec) + eps I  -> sA
  for (int idx = tid; idx < 4096; idx += BLOCK) {
    int i = idx >> 6, jj = idx & 63;
    int lo = (i < jj) ? i : jj, hi = (i < jj) ? jj : i;
    sA[i * LD + jj] = svec[triOff(lo) + (hi - lo)] + ((i == jj) ? EPSF : 0.0f);
  }
  __syncthreads();

  // ===== exp(mtil) via scaling & squaring (replaces 2nd Jacobi eigh) =====
  {
    const int ti = tid >> 4;          // 0..15 (row tile)
    const int tj = tid & 15;          // 0..15 (col tile)
    const int r0 = ti << 2, c0 = tj << 2;

    // inf-norm (symmetric => bounds spectral norm)
    if (tid < 64) {
      float rs = 0.0f;
      for (int jj2 = 0; jj2 < 64; ++jj2) rs += fabsf(sA[tid * LD + jj2]);
      red[tid] = rs;
    }
    __syncthreads();
    if (tid < 32) red[tid] = fmaxf(red[tid], red[tid + 32]);
    __syncthreads();
    if (tid < 16) red[tid] = fmaxf(red[tid], red[tid + 16]);
    __syncthreads();
    if (tid < 8)  red[tid] = fmaxf(red[tid], red[tid + 8]);
    __syncthreads();
    if (tid < 4)  red[tid] = fmaxf(fmaxf(red[tid], red[tid + 4]),
                                   fmaxf(red[tid + 2] , red[(tid + 2) & 3]));
    __syncthreads();
    float R = fmaxf(fmaxf(red[0], red[1]), fmaxf(red[2], red[3]));

    int kpow = 0;
    float t = R;
    while (t > 0.25f && kpow < 24) { t *= 0.5f; ++kpow; }
    const float sc = ldexpf(1.0f, -kpow);

    // X = mtil * 2^-k (in place, sA)
    for (int idx = tid; idx < 4096; idx += BLOCK) {
      int i = idx >> 6, jj = idx & 63;
      sA[i * LD + jj] *= sc;
    }
    __syncthreads();

    // E = I + X + sum_{d=2..8} X^d/d!   (E in registers, powers ping in sT)
    float E[16];
    #pragma unroll
    for (int rr = 0; rr < 4; ++rr)
      #pragma unroll
      for (int c = 0; c < 4; ++c)
        E[rr * 4 + c] = ((r0 + rr) == (c0 + c) ? 1.0f : 0.0f) + sA[(r0 + rr) * LD + c0 + c];

    const float coef[7] = { 0.5f, 0.16666667f, 0.041666668f, 0.008333334f,
                            0.0013888889f, 1.9841270e-4f, 2.4801587e-5f };

    // d = 2: P = X*X  (reads sA only; sT dead after svec consumed)
    {
      float acc[16];
      #pragma unroll
      for (int u = 0; u < 16; ++u) acc[u] = 0.0f;
      for (int kk = 0; kk < 64; ++kk) {
        float a0 = sA[(r0 + 0) * LD + kk], a1 = sA[(r0 + 1) * LD + kk];
        float a2 = sA[(r0 + 2) * LD + kk], a3 = sA[(r0 + 3) * LD + kk];
        float b0 = sA[kk * LD + c0 + 0], b1v = sA[kk * LD + c0 + 1];
        float b2v = sA[kk * LD + c0 + 2], b3 = sA[kk * LD + c0 + 3];
        acc[0] += a0 * b0;  acc[1] += a0 * b1v;  acc[2] += a0 * b2v;  acc[3] += a0 * b3;
        acc[4] += a1 * b0;  acc[5] += a1 * b1v;  acc[6] += a1 * b2v;  acc[7] += a1 * b3;
        acc[8] += a2 * b0;  acc[9] += a2 * b1v;  acc[10] += a2 * b2v; acc[11] += a2 * b3;
        acc[12] += a3 * b0; acc[13] += a3 * b1v; acc[14] += a3 * b2v; acc[15] += a3 * b3;
      }
      __syncthreads();
      #pragma unroll
      for (int rr = 0; rr < 4; ++rr)
        #pragma unroll
        for (int c = 0; c < 4; ++c) {
          sT[(r0 + rr) * LD + c0 + c] = acc[rr * 4 + c];
          E[rr * 4 + c] += coef[0] * acc[rr * 4 + c];
        }
      __syncthreads();
    }
    // d = 3..8: P = P*X (in place via register staging)
    for (int d = 3; d <= 8; ++d) {
      float acc[16];
      #pragma unroll
      for (int u = 0; u < 16; ++u) acc[u] = 0.0f;
      for (int kk = 0; kk < 64; ++kk) {
        float a0 = sT[(r0 + 0) * LD + kk], a1 = sT[(r0 + 1) * LD + kk];
        float a2 = sT[(r0 + 2) * LD + kk], a3 = sT[(r0 + 3) * LD + kk];
        float b0 = sA[kk * LD + c0 + 0], b1v = sA[kk * LD + c0 + 1];
        float b2v = sA[kk * LD + c0 + 2], b3 = sA[kk * LD + c0 + 3];
        acc[0] += a0 * b0;  acc[1] += a0 * b1v;  acc[2] += a0 * b2v;  acc[3] += a0 * b3;
        acc[4] += a1 * b0;  acc[5] += a1 * b1v;  acc[6] += a1 * b2v;  acc[7] += a1 * b3;
        acc[8] += a2 * b0;  acc[9] += a2 * b1v;  acc[10] += a2 * b2v; acc[11] += a2 * b3;
        acc[12] += a3 * b0; acc[13] += a3 * b1v; acc[14] += a3 * b2v; acc[15] += a3 * b3;
      }
      __syncthreads();                       // all reads of sT done
      const float cd = coef[d - 2];
      #pragma unroll
      for (int rr = 0; rr < 4; ++rr)
        #pragma unroll
        for (int c = 0; c < 4; ++c) {
          sT[(r0 + rr) * LD + c0 + c] = acc[rr * 4 + c];
          E[rr * 4 + c] += cd * acc[rr * 4 + c];
        }
      __syncthreads();
    }
    // E -> sT
    #pragma unroll
    for (int rr = 0; rr < 4; ++rr)
      #pragma unroll
      for (int c = 0; c < 4; ++c)
        sT[(r0 + rr) * LD + c0 + c] = E[rr * 4 + c];
    __syncthreads();
    // square k times (in place via register staging)
    for (int itq = 0; itq < kpow; ++itq) {
      float acc[16];
      #pragma unroll
      for (int u = 0; u < 16; ++u) acc[u] = 0.0f;
      for (int kk = 0; kk < 64; ++kk) {
        float a0 = sT[(r0 + 0) * LD + kk], a1 = sT[(r0 + 1) * LD + kk];
        float a2 = sT[(r0 + 2) * LD + kk], a3 = sT[(r0 + 3) * LD + kk];
        float b0 = sT[kk * LD + c0 + 0], b1v = sT[kk * LD + c0 + 1];
        float b2v = sT[kk * LD + c0 + 2], b3 = sT[kk * LD + c0 + 3];
        acc[0] += a0 * b0;  acc[1] += a0 * b1v;  acc[2] += a0 * b2v;  acc[3] += a0 * b3;
        acc[4] += a1 * b0;  acc[5] += a1 * b1v;  acc[6] += a1 * b2v;  acc[7] += a1 * b3;
        acc[8] += a2 * b0;  acc[9] += a2 * b1v;  acc[10] += a2 * b2v; acc[11] += a2 * b3;
        acc[12] += a3 * b0; acc[13] += a3 * b1v; acc[14] += a3 * b2v; acc[15] += a3 * b3;
      }
      __syncthreads();
      #pragma unroll
      for (int rr = 0; rr < 4; ++rr)
        #pragma unroll
        for (int c = 0; c < 4; ++c)
          sT[(r0 + rr) * LD + c0 + c] = acc[rr * 4 + c];
      __syncthreads();
    }
  }
  // exp_a now in sT

  gemm_gS(ref, sT, sA);           // A = M2 = ref @ exp_a
  __syncthreads();

  // --- SPD shift: shift = max(EPS - lambda_min(sym_lower(M2)), 0)
  // Fast path: LDL^T PD-test of C = sym_lower(M2) - EPS*I (workspace sT).
  {
    for (int idx = tid; idx < 4096; idx += BLOCK) {
      int i = idx >> 6, jj = idx & 63;
      float v = (i >= jj) ? sA[i * LD + jj] : sA[jj * LD + i];
      sT[i * LD + jj] = v - ((i == jj) ? EPSF : 0.0f);
    }
    __syncthreads();

    bool pd = true;
    const int col = tid & 63;
    const int rw  = tid >> 6;
    for (int k = 0; k < 64; ++k) {
      float d = sT[k * LD + k];
      if (d <= 1e-30f) { pd = false; break; }
      if (col > k) {
        float ljk = sT[col * LD + k] / d;
        for (int i = k + 1 + rw; i < 64; i += 4) {
          float aik = sT[i * LD + k];
          sT[i * LD + col] -= aik * ljk;
        }
      }
      __syncthreads();
    }

    if (pd) {
      if (tid == 0) shiftv = 0.0f;
      __syncthreads();
    } else {
      __syncthreads();
      // Fallback: eigenvalues-only Jacobi on sym_lower(M2)
      for (int idx = tid; idx < 4096; idx += BLOCK) {
        int i = idx >> 6, jj = idx & 63;
        sT[i * LD + jj] = (i >= jj) ? sA[i * LD + jj] : sA[jj * LD + i];
      }
      __syncthreads();
      jacobi64<false>(sT, nullptr, cb, sb, red, RELTOL_VALS);
      if (tid == 0) {
        float mn = sT[0];
        for (int i = 1; i < 64; ++i) mn = fminf(mn, sT[i * LD + i]);
        shiftv = fmaxf(EPSF - mn, 0.0f);
      }
      __syncthreads();
    }
  }

  const float sh = shiftv;
  for (int idx = tid; idx < 4096; idx += BLOCK) {
    int i = idx >> 6, jj = idx & 63;
    out[b * 4096 + idx] = sA[i * LD + jj] + ((i == jj) ? sh : 0.0f);
  }
}

extern "C" void kernel_launch(void* const* d_in, const int* in_sizes, int n_in,
                              void* d_out, int out_size, void* d_ws, size_t ws_size,
                              hipStream_t stream) {
  (void)in_sizes; (void)n_in; (void)out_size; (void)ws_size;
  const float* x    = (const float*)d_in[0];
  const float* ref  = (const float*)d_in[1];
  const float* w1   = (const float*)d_in[2];
  const float* b1   = (const float*)d_in[3];
  const float* g1   = (const float*)d_in[4];
  const float* bb1  = (const float*)d_in[5];
  const float* w2   = (const float*)d_in[6];
  const float* b2   = (const float*)d_in[7];
  const float* g2   = (const float*)d_in[8];
  const float* bb2  = (const float*)d_in[9];
  const float* muw  = (const float*)d_in[10];
  const float* mub  = (const float*)d_in[11];
  const float* lvw  = (const float*)d_in[12];
  const float* lvb  = (const float*)d_in[13];
  const float* dw1  = (const float*)d_in[14];
  const float* db1  = (const float*)d_in[15];
  const float* dg1  = (const float*)d_in[16];
  const float* dbb1 = (const float*)d_in[17];
  const float* dw2  = (const float*)d_in[18];
  const float* db2  = (const float*)d_in[19];
  const float* dg2  = (const float*)d_in[20];
  const float* dbb2 = (const float*)d_in[21];
  const float* dw3  = (const float*)d_in[22];
  const float* db3  = (const float*)d_in[23];
  float* out = (float*)d_out;
  float* ws  = (float*)d_ws;   // rm (4096 floats) + rp (4096 floats)

  vae_prep<<<1, BLOCK, 0, stream>>>(ref, ws);
  vae_main<<<BATCH, BLOCK, 0, stream>>>(x, ref, ws,
      w1, b1, g1, bb1, w2, b2, g2, bb2, muw, mub, lvw, lvb,
      dw1, db1, dg1, dbb1, dw2, db2, dg2, dbb2, dw3, db3, out);
}